// Round 1
// baseline (119.253 us; speedup 1.0000x reference)
//
#include <hip/hip_runtime.h>

typedef unsigned short ushort_t;
typedef __bf16 bf16_8 __attribute__((ext_vector_type(8)));
typedef float f32x4 __attribute__((ext_vector_type(4)));

#define VOCAB 4101
#define KPAD  4160   // 65 * 64
#define NROWS 3072   // 1024 * 3
#define HDIM  768
#define ODIM  256

// ---- helpers -------------------------------------------------------------

static __device__ __forceinline__ unsigned short f2bf(float f) {
  // round-to-nearest-even fp32 -> bf16 bits
  unsigned int u = __float_as_uint(f);
  unsigned int r = (u + 0x7fffu + ((u >> 16) & 1u)) >> 16;
  return (unsigned short)r;
}

static __device__ __forceinline__ void async_copy16(const void* g, void* l) {
  __builtin_amdgcn_global_load_lds(
      (const __attribute__((address_space(1))) void*)g,
      (__attribute__((address_space(3))) void*)l, 16, 0, 0);
}

// ---- kernel 1: per-row histogram -> bf16 integer counts + scale ----------

__global__ __launch_bounds__(256)
void hist_kernel(const int* __restrict__ X, ushort_t* __restrict__ A,
                 float* __restrict__ scales) {
  const int r = blockIdx.x;                 // row 0..3071
  __shared__ unsigned int h[KPAD];
  for (int i = threadIdx.x; i < KPAD; i += 256) h[i] = 0u;
  __syncthreads();

  const int4* xp = reinterpret_cast<const int4*>(X + (size_t)r * 4096);
  #pragma unroll
  for (int i = 0; i < 4; ++i) {
    int4 v = xp[i * 256 + threadIdx.x];     // coalesced 16B loads
    atomicAdd(&h[v.x], 1u);
    atomicAdd(&h[v.y], 1u);
    atomicAdd(&h[v.z], 1u);
    atomicAdd(&h[v.w], 1u);
  }
  __syncthreads();

  const unsigned int ignored = h[0] + h[1] + h[2] + h[3] + h[4];
  const float s = 10.0f / (float)(4096u - ignored);   // kept-token count > 0 always
  if (threadIdx.x == 0) scales[r] = s;

  ushort_t* Ar = A + (size_t)r * KPAD;
  for (int i = threadIdx.x; i < KPAD; i += 256) {
    unsigned int c = (i >= 5 && i < VOCAB) ? h[i] : 0u;
    Ar[i] = f2bf((float)c);                 // small integer -> exact in bf16
  }
}

// ---- kernel 2: transpose + fp32->bf16 convert: src[K][N] -> dst[N][Kpad] -

__global__ __launch_bounds__(256)
void transpose_convert(const float* __restrict__ src, ushort_t* __restrict__ dst,
                       int K, int N, int Kpad) {
  __shared__ ushort_t tile[64][65];
  const int kb = blockIdx.x * 64;
  const int nb = blockIdx.y * 64;
  const int tr = threadIdx.x >> 6;          // 0..3
  const int tc = threadIdx.x & 63;          // 0..63
  #pragma unroll
  for (int i = 0; i < 16; ++i) {
    int r = i * 4 + tr;                     // 0..63
    int k = kb + r;
    float v = (k < K) ? src[(size_t)k * N + nb + tc] : 0.0f;
    tile[r][tc] = f2bf(v);
  }
  __syncthreads();
  #pragma unroll
  for (int i = 0; i < 16; ++i) {
    int r = i * 4 + tr;                     // output n-row within tile
    dst[(size_t)(nb + r) * Kpad + kb + tc] = tile[tc][r];
  }
}

// ---- kernel 3/4: bf16 MFMA GEMM, m97 2-barrier structure -----------------
// C[M][N] = A[M][K] * Bt[N][K]^T ; BM=128, BN=64, BK=64, 256 thr (2x2 waves)
// EPI 0: v = acc*scales[row] + bias[col]; relu; -> bf16 H[row*768+col]
// EPI 1: v = acc + bias[col]; -> fp32 out[(row%3)*262144 + (row/3)*256 + col]

template <int EPI>
__global__ __launch_bounds__(256)
void gemm_bf16(const ushort_t* __restrict__ A, int lda,
               const ushort_t* __restrict__ Bt, int ldb,
               int nK,
               const float* __restrict__ scales,
               const float* __restrict__ bias,
               void* __restrict__ outp) {
  __shared__ __align__(16) ushort_t Alds[128 * 64];
  __shared__ __align__(16) ushort_t Blds[64 * 64];
  const int tid  = threadIdx.x;
  const int lane = tid & 63;
  const int wv   = tid >> 6;      // 0..3
  const int wr   = wv >> 1;       // wave row (0..1)  -> 64 rows each
  const int wc   = wv & 1;        // wave col (0..1)  -> 32 cols each
  const int m0   = blockIdx.x * 128;
  const int n0   = blockIdx.y * 64;

  f32x4 acc[4][2];
  #pragma unroll
  for (int m = 0; m < 4; ++m)
    #pragma unroll
    for (int n = 0; n < 2; ++n)
      acc[m][n] = (f32x4){0.f, 0.f, 0.f, 0.f};

  for (int kt = 0; kt < nK; ++kt) {
    const int k0 = kt * 64;
    // stage A tile [128][64] bf16, linear LDS, 16B per lane
    #pragma unroll
    for (int i = 0; i < 4; ++i) {
      const int e = i * 2048 + wv * 512 + lane * 8;   // bf16 elem idx in tile
      const int row = e >> 6, col = e & 63;
      async_copy16(A + (size_t)(m0 + row) * lda + k0 + col, (char*)Alds + 2 * e);
    }
    // stage B tile [64][64]
    #pragma unroll
    for (int i = 0; i < 2; ++i) {
      const int e = i * 2048 + wv * 512 + lane * 8;
      const int row = e >> 6, col = e & 63;
      async_copy16(Bt + (size_t)(n0 + row) * ldb + k0 + col, (char*)Blds + 2 * e);
    }
    __syncthreads();   // compiler drains vmcnt before barrier

    #pragma unroll
    for (int kk = 0; kk < 2; ++kk) {
      bf16_8 af[4], bfr[2];
      #pragma unroll
      for (int m = 0; m < 4; ++m)
        af[m] = *(const bf16_8*)&Alds[(wr * 64 + m * 16 + (lane & 15)) * 64 +
                                      kk * 32 + (lane >> 4) * 8];
      #pragma unroll
      for (int n = 0; n < 2; ++n)
        bfr[n] = *(const bf16_8*)&Blds[(wc * 32 + n * 16 + (lane & 15)) * 64 +
                                       kk * 32 + (lane >> 4) * 8];
      #pragma unroll
      for (int m = 0; m < 4; ++m)
        #pragma unroll
        for (int n = 0; n < 2; ++n)
          acc[m][n] = __builtin_amdgcn_mfma_f32_16x16x32_bf16(af[m], bfr[n],
                                                              acc[m][n], 0, 0, 0);
    }
    __syncthreads();
  }

  // epilogue: D col = lane&15, row = 4*(lane>>4)+reg   [verified layout]
  const int rbase = (lane >> 4) * 4;
  const int cf    = lane & 15;
  #pragma unroll
  for (int m = 0; m < 4; ++m) {
    #pragma unroll
    for (int n = 0; n < 2; ++n) {
      #pragma unroll
      for (int reg = 0; reg < 4; ++reg) {
        const int gr = m0 + wr * 64 + m * 16 + rbase + reg;
        const int gc = n0 + wc * 32 + n * 16 + cf;
        float v = acc[m][n][reg];
        if constexpr (EPI == 0) {
          v = fmaxf(v * scales[gr] + bias[gc], 0.0f);
          ((ushort_t*)outp)[(size_t)gr * HDIM + gc] = f2bf(v);
        } else {
          v += bias[gc];
          ((float*)outp)[(size_t)(gr % 3) * (1024 * ODIM) +
                         (size_t)(gr / 3) * ODIM + gc] = v;
        }
      }
    }
  }
}

// ---- launch --------------------------------------------------------------

extern "C" void kernel_launch(void* const* d_in, const int* in_sizes, int n_in,
                              void* d_out, int out_size, void* d_ws, size_t ws_size,
                              hipStream_t stream) {
  const int*   X  = (const int*)d_in[0];     // [1024][3][4096] int32
  const float* W1 = (const float*)d_in[1];   // [4101][768]
  const float* b1 = (const float*)d_in[2];   // [768]
  const float* W2 = (const float*)d_in[3];   // [768][256]
  const float* b2 = (const float*)d_in[4];   // [256]
  float* out = (float*)d_out;                // [3][1024][256]

  char* ws = (char*)d_ws;
  ushort_t* A      = (ushort_t*)(ws);                  // 3072*4160 bf16 = 25,559,040 B
  ushort_t* W1T    = (ushort_t*)(ws + 25559040);       //  768*4160 bf16 =  6,389,760 B
  ushort_t* H      = (ushort_t*)(ws + 31948800);       // 3072*768  bf16 =  4,718,592 B
  ushort_t* W2T    = (ushort_t*)(ws + 36667392);       //  256*768  bf16 =    393,216 B
  float*    scales = (float*)   (ws + 37060608);       // 3072 fp32

  hist_kernel<<<NROWS, 256, 0, stream>>>(X, A, scales);
  transpose_convert<<<dim3(KPAD / 64, HDIM / 64), 256, 0, stream>>>(W1, W1T, VOCAB, HDIM, KPAD);
  transpose_convert<<<dim3(HDIM / 64, ODIM / 64), 256, 0, stream>>>(W2, W2T, HDIM, ODIM, HDIM);

  gemm_bf16<0><<<dim3(NROWS / 128, HDIM / 64), 256, 0, stream>>>(
      A, KPAD, W1T, KPAD, KPAD / 64, scales, b1, (void*)H);
  gemm_bf16<1><<<dim3(NROWS / 128, ODIM / 64), 256, 0, stream>>>(
      H, HDIM, W2T, HDIM, HDIM / 64, nullptr, b2, (void*)out);
}